// Round 8
// baseline (98.867 us; speedup 1.0000x reference)
//
#include <hip/hip_runtime.h>
#include <hip/hip_fp16.h>

// AdaptiveHighPassFilter: conv3x3(64->9, zero-pad) -> softmax(taps) -> hamming
// renorm -> CARAFE(3x3, reflect) -> 2x - lowpass.
//
// R13 = R12 with the prep kernel MERGED into the main kernel (single
// dispatch). Unlike R10's failed merge (144 address-divergent global loads
// per thread), each block loads W COALESCED (5184 f32 linear, ~20/thread),
// converts to fp16 and scatters into the A-fragment layout in LDS (reusing
// sx BEFORE tile staging); lanes read their 18 fragments as conflict-free
// ds_read_b128; barrier; sx is then overwritten by tile staging as usual.
// Correctness: fragment slots for fm>=9 stay as LDS garbage -- A-row m only
// feeds D-row m, and rows 9..15 of D are never read (nval mask), so no
// zero-fill needed. Saves the prep dispatch + graph edge (~2-3us of the
// ~12.7us controllable budget; 2x 268MB poison fills = ~86us are fixed).
//
// R12: __launch_bounds__(256,2) -- (256,4) made the backend squeeze to 64
// VGPR and spill (FETCH 16.7->84MB). R11: 256-thr blocks, 2 rows/wave,
// 16 waves/CU. R10: 4-deep row ring buffer + dual MFMA chains.
// R9: fp16 pipeline (pk_fma carafe via op_sel, pk epilogue, 16x16x32_f16).
// R7: cvt_pk staging pack. R5-R6: carafe from conv's own B-fragments, mask
// broadcast via 5 shuffles, 16x8 tiles, XCD swizzle.

typedef __attribute__((ext_vector_type(8))) short short8;
typedef __attribute__((ext_vector_type(4))) float floatx4;
typedef __attribute__((ext_vector_type(4))) unsigned uint4v;

#define IH 128
#define IW 128
#define CCH 64
#define TSX 16
#define TSY 8
#define TPX 18
#define TPY 10
#define CSH 72   // shorts per position: 144B row, 16B-aligned, bank stride 4

// 1-instruction pack of two f32 -> packed f16x2 (lo = a, hi = b), RTZ
__device__ __forceinline__ unsigned cvtpkh(float a, float b) {
    unsigned r;
    asm("v_cvt_pkrtz_f16_f32 %0, %1, %2" : "=v"(r) : "v"(a), "v"(b));
    return r;
}
// l_pair += x_pair * m.lo   (f16 packed, mask lo-half broadcast via op_sel)
__device__ __forceinline__ unsigned pkfma_lo(unsigned x2, unsigned m2, unsigned acc) {
    unsigned d;
    asm("v_pk_fma_f16 %0, %1, %2, %3 op_sel:[0,0,0] op_sel_hi:[1,0,1]"
        : "=v"(d) : "v"(x2), "v"(m2), "v"(acc));
    return d;
}
// l_pair += x_pair * m.hi
__device__ __forceinline__ unsigned pkfma_hi(unsigned x2, unsigned m2, unsigned acc) {
    unsigned d;
    asm("v_pk_fma_f16 %0, %1, %2, %3 op_sel:[0,1,0] op_sel_hi:[1,1,1]"
        : "=v"(d) : "v"(x2), "v"(m2), "v"(acc));
    return d;
}
// o_pair = c_pair * 2.0 - l_pair   (f16 packed)
__device__ __forceinline__ unsigned pk2xml(unsigned c2, unsigned two2, unsigned l2) {
    unsigned d;
    asm("v_pk_fma_f16 %0, %1, %2, %3 neg_lo:[0,0,1] neg_hi:[0,0,1]"
        : "=v"(d) : "v"(c2), "v"(two2), "v"(l2));
    return d;
}
__device__ __forceinline__ float h2f_lo(unsigned u) {
    return __half2float(__ushort_as_half((unsigned short)(u & 0xFFFFu)));
}
__device__ __forceinline__ float h2f_hi(unsigned u) {
    return __half2float(__ushort_as_half((unsigned short)(u >> 16)));
}
__device__ __forceinline__ unsigned short f2h(float f) {
    return __half_as_ushort(__float2half(f));   // RNE
}

__global__ __launch_bounds__(256, 2) void ahpf_kernel(
    const float* __restrict__ x, const float* __restrict__ Wg,
    const float* __restrict__ bias, float* __restrict__ out)
{
    __shared__ __align__(16) unsigned short sx[TPY * TPX * CSH];  // 25,920 B

    const int tid  = threadIdx.x;
    const int lane = tid & 63;
    const int wv   = tid >> 6;          // 0..3

    // XCD swizzle: XCD k gets the 128 tiles of image k
    const unsigned flat = blockIdx.x + 8u * (blockIdx.y + 16u * blockIdx.z);
    const unsigned nid  = (flat & 7u) * 128u + (flat >> 3);
    const int bx = nid & 7, by = (nid >> 3) & 15, bz = nid >> 7;

    const int ty0 = by * TSY;
    const int tx0 = bx * TSX;
    const size_t hw = (size_t)IH * IW;
    const float* xb = x + (size_t)bz * CCH * hw;

    const int fm = lane & 15;   // conv: pixel col n / A row m
    const int fq = lane >> 4;

    // ---- phase W: coalesced W load -> fp16 A-fragment scatter into sx.
    // Fragment layout (shorts): sx[s*512 + l*8 + jj], l = fq*16 + fm.
    // Slots with (l&15)>=9 stay as garbage: A-row m only feeds D-row m and
    // rows 9..15 of D are never read.
    {
        const int WTOT = 9 * 64 * 9;                 // 5184 floats
#pragma unroll
        for (int k = 0; k < 21; ++k) {
            const int i = k * 256 + tid;
            if (i < WTOT) {
                const float v = Wg[i];
                const int fmi = i / 576;             // filter 0..8
                const int rem = i - fmi * 576;
                const int c   = rem / 9;             // channel 0..63
                const int tp  = rem - c * 9;         // tap 0..8
                const int sl  = tp * 2 + (c >> 5);
                const int li  = ((c >> 3) & 3) * 16 + fmi;
                sx[sl * 512 + li * 8 + (c & 7)] = f2h(v);
            }
        }
    }
    __syncthreads();

    // ---- A-fragments: 18 conflict-free ds_read_b128 per lane
    short8 afr[18];
#pragma unroll
    for (int s = 0; s < 18; ++s)
        afr[s] = *(const short8*)&sx[s * 512 + lane * 8];
    float bq[4];
#pragma unroll
    for (int r = 0; r < 4; ++r) {
        const int t = fq * 4 + r;
        bq[r] = (t < 9) ? bias[t] : 0.0f;
    }
    __syncthreads();   // all fragment reads complete before sx is overwritten

    // ---- stage reflect-padded tile fp16 [pos][c]; slots = 8ch x 4pos
    {
        int gx0 = tx0 - 4;
        if (gx0 < 0) gx0 = 0;
        if (gx0 > IW - 24) gx0 = IW - 24;
        const bool xlo = (bx == 0), xhi = (bx == 7);
        const int cg8 = tid & 7;                 // fixed per thread
#pragma unroll
        for (int it = 0; it < 2; ++it) {
            const int s = it * 256 + tid;        // 480 slots total
            if (s >= 480) break;
            const int u = s >> 3;                // 0..59
            const int y = u / 6, xg = u - 6 * y;
            int gy = ty0 + y - 1;
            gy = gy < 0 ? -gy : (gy >= IH ? 2 * IH - 2 - gy : gy);
            const float* src = xb + (size_t)(cg8 * 8) * hw
                             + (size_t)gy * IW + gx0 + 4 * xg;
            float4 v[8];
#pragma unroll
            for (int jj = 0; jj < 8; ++jj)
                v[jj] = *(const float4*)(src + (size_t)jj * hw);
            const int xbase = gx0 + 4 * xg - tx0 + 1;
#pragma unroll
            for (int e = 0; e < 4; ++e) {
                const float fe[8] = {
                    ((const float*)&v[0])[e], ((const float*)&v[1])[e],
                    ((const float*)&v[2])[e], ((const float*)&v[3])[e],
                    ((const float*)&v[4])[e], ((const float*)&v[5])[e],
                    ((const float*)&v[6])[e], ((const float*)&v[7])[e]};
                uint4v pk;
                pk.x = cvtpkh(fe[0], fe[1]); pk.y = cvtpkh(fe[2], fe[3]);
                pk.z = cvtpkh(fe[4], fe[5]); pk.w = cvtpkh(fe[6], fe[7]);
                const int gxe = gx0 + 4 * xg + e;
                const int xx = xbase + e;
                if (xx >= 0 && xx < TPX)
                    *(uint4v*)&sx[(y * TPX + xx) * CSH + cg8 * 8] = pk;
                if (xlo && gxe == 1)
                    *(uint4v*)&sx[(y * TPX + 0) * CSH + cg8 * 8] = pk;
                if (xhi && gxe == 126)
                    *(uint4v*)&sx[(y * TPX + 17) * CSH + cg8 * 8] = pk;
            }
        }
    }
    __syncthreads();

    const bool border = (bx == 0) | (bx == 7) | (by == 0) | (by == 15);
    const int n = fm;

    // 4-deep dy-row ring buffer; all indices compile-time after unroll.
    // buffer b holds one dy-row: 3 dx positions x 2 ch-halves = 6 frags.
    short8 rbuf[24];
#define FR(dy1, dx1, half) rbuf[(((rr + (dy1)) & 3) * 6) + (dx1) * 2 + (half)]
#define LDSRD(row, dx1, half) \
    (*(const short8*)&sx[((row) * TPX + (n + (dx1))) * CSH + (half) * 32 + fq * 8])

    // carafe: one tap, 16 channels = 8 pk_fma (mask half broadcast by op_sel)
#define CARAFE_TAP(dy1, dx1, qq, HALF)                                       \
    {                                                                        \
        const uint4v A  = *(const uint4v*)&FR(dy1, dx1, 0);                  \
        const uint4v Bv = *(const uint4v*)&FR(dy1, dx1, 1);                  \
        _Pragma("unroll")                                                    \
        for (int u = 0; u < 4; ++u) {                                        \
            l[u]     = pkfma_##HALF(A[u],  qq, l[u]);                        \
            l[4 + u] = pkfma_##HALF(Bv[u], qq, l[4 + u]);                    \
        }                                                                    \
    }

    // ---- per row (2 rows/wave): conv MFMA (dual chains) -> softmax ->
    //      broadcast -> carafe
#pragma unroll
    for (int rr = 0; rr < 2; ++rr) {
        const int R = wv * 2 + rr;
        const int h = ty0 + R, w = tx0 + n;

        if (rr == 0) {
            // fill bufs 0,1,2 with dy-rows R+0,R+1,R+2 (LDS rows)
#pragma unroll
            for (int dy1 = 0; dy1 < 3; ++dy1)
#pragma unroll
                for (int dx1 = 0; dx1 < 3; ++dx1) {
                    FR(dy1, dx1, 0) = LDSRD(R + dy1, dx1, 0);
                    FR(dy1, dx1, 1) = LDSRD(R + dy1, dx1, 1);
                }
        }

        floatx4 ac0 = {0.f, 0.f, 0.f, 0.f};
        floatx4 ac1 = {0.f, 0.f, 0.f, 0.f};
        if (border) {
#pragma unroll
            for (int dy1 = 0; dy1 < 3; ++dy1)
#pragma unroll
                for (int dx1 = 0; dx1 < 3; ++dx1) {
                    const int hy = h + dy1 - 1, wx = w + dx1 - 1;
                    const bool oob = (hy < 0) | (hy >= IH) | (wx < 0) | (wx >= IW);
                    short8 b0 = FR(dy1, dx1, 0);
                    short8 b1 = FR(dy1, dx1, 1);
                    if (oob) { b0 = (short8)0; b1 = (short8)0; }
                    const int s2 = 2 * (3 * dy1 + dx1);
                    ac0 = __builtin_amdgcn_mfma_f32_16x16x32_f16(afr[s2],     b0, ac0, 0, 0, 0);
                    ac1 = __builtin_amdgcn_mfma_f32_16x16x32_f16(afr[s2 + 1], b1, ac1, 0, 0, 0);
                }
        } else {
#pragma unroll
            for (int dy1 = 0; dy1 < 3; ++dy1)
#pragma unroll
                for (int dx1 = 0; dx1 < 3; ++dx1) {
                    const int s2 = 2 * (3 * dy1 + dx1);
                    ac0 = __builtin_amdgcn_mfma_f32_16x16x32_f16(afr[s2],     FR(dy1, dx1, 0), ac0, 0, 0, 0);
                    ac1 = __builtin_amdgcn_mfma_f32_16x16x32_f16(afr[s2 + 1], FR(dy1, dx1, 1), ac1, 0, 0, 0);
                }
        }
        const floatx4 acc = ac0 + ac1;

        // prefetch next row's dy=+1 into the (dead) 4th buffer; max LDS row
        // = wv*2+3 = 9 < TPY. lgkm latency overlaps softmax + broadcast.
        if (rr < 1) {
#pragma unroll
            for (int dx1 = 0; dx1 < 3; ++dx1) {
                rbuf[(((rr + 3) & 3) * 6) + dx1 * 2 + 0] = LDSRD(R + 3, dx1, 0);
                rbuf[(((rr + 3) & 3) * 6) + dx1 * 2 + 1] = LDSRD(R + 3, dx1, 1);
            }
        }

        // softmax*hamming, denom-cancelled; lane holds taps fq*4+r of pixel n
        auto hamt = [](int t) {
            const float a = (t / 3 == 1) ? 1.f : 0.08f;
            const float b = (t % 3 == 1) ? 1.f : 0.08f;
            return a * b;
        };
        const int nval = (fq < 2) ? 4 : (fq == 2 ? 1 : 0);
        float e0 = 0, e1 = 0, e2 = 0, e3 = 0, ssum = 0;
        if (nval >= 1) { e0 = __expf(acc[0] + bq[0]) * hamt(fq * 4 + 0); ssum += e0; }
        if (nval >= 4) { e1 = __expf(acc[1] + bq[1]) * hamt(fq * 4 + 1); ssum += e1;
                         e2 = __expf(acc[2] + bq[2]) * hamt(fq * 4 + 2); ssum += e2;
                         e3 = __expf(acc[3] + bq[3]) * hamt(fq * 4 + 3); ssum += e3; }
        ssum += __shfl_xor(ssum, 16);
        ssum += __shfl_xor(ssum, 32);
        const float inv = 1.0f / ssum;

        // broadcast 9 taps to every lane of pixel n as f16 TAP-PAIRS:
        // q0=(m0,m1) q1=(m2,m3) q2=(m4,m5) q3=(m6,m7) q4=(m8,0)
        const unsigned p01 = cvtpkh(e0 * inv, e1 * inv);
        const unsigned p23 = cvtpkh(e2 * inv, e3 * inv);
        const unsigned q0 = (unsigned)__shfl((int)p01, n);
        const unsigned q1 = (unsigned)__shfl((int)p23, n);
        const unsigned q2 = (unsigned)__shfl((int)p01, 16 + n);
        const unsigned q3 = (unsigned)__shfl((int)p23, 16 + n);
        const unsigned q4 = (unsigned)__shfl((int)p01, 32 + n);

        // carafe from registers via packed f16 fma: ch {8fq..}+{32+8fq..}
        unsigned l[8];
#pragma unroll
        for (int i = 0; i < 8; ++i) l[i] = 0u;
        CARAFE_TAP(0, 0, q0, lo);   // tap 0
        CARAFE_TAP(0, 1, q0, hi);   // tap 1
        CARAFE_TAP(0, 2, q1, lo);   // tap 2
        CARAFE_TAP(1, 0, q1, hi);   // tap 3
        CARAFE_TAP(1, 1, q2, lo);   // tap 4
        CARAFE_TAP(1, 2, q2, hi);   // tap 5
        CARAFE_TAP(2, 0, q3, lo);   // tap 6
        CARAFE_TAP(2, 1, q3, hi);   // tap 7
        CARAFE_TAP(2, 2, q4, lo);   // tap 8 (hi mask = 0)

        const uint4v c0 = *(const uint4v*)&FR(1, 1, 0);   // center tap (t=4)
        const uint4v c1 = *(const uint4v*)&FR(1, 1, 1);
        const unsigned TWO2 = 0x40004000u;                // (2.0h, 2.0h)
        float* ob = out + (size_t)bz * CCH * hw + (size_t)h * IW + w
                  + (size_t)(8 * fq) * hw;
#pragma unroll
        for (int q = 0; q < 4; ++q) {
            const unsigned oe = pk2xml(c0[q], TWO2, l[q]);
            const unsigned oo = pk2xml(c1[q], TWO2, l[4 + q]);
            ob[(size_t)(2 * q) * hw]          = h2f_lo(oe);
            ob[(size_t)(2 * q + 1) * hw]      = h2f_hi(oe);
            ob[(size_t)(32 + 2 * q) * hw]     = h2f_lo(oo);
            ob[(size_t)(32 + 2 * q + 1) * hw] = h2f_hi(oo);
        }
    }
#undef CARAFE_TAP
#undef LDSRD
#undef FR
}

extern "C" void kernel_launch(void* const* d_in, const int* in_sizes, int n_in,
                              void* d_out, int out_size, void* d_ws, size_t ws_size,
                              hipStream_t stream) {
    const float* x    = (const float*)d_in[0];
    const float* Wg   = (const float*)d_in[1];
    const float* bias = (const float*)d_in[2];
    float* out        = (float*)d_out;
    const int B = in_sizes[0] / (CCH * IH * IW);
    dim3 grid(8, 16, B);
    ahpf_kernel<<<grid, dim3(256, 1, 1), 0, stream>>>(x, Wg, bias, out);
}

// Round 9
// 98.645 us; speedup vs baseline: 1.0023x; 1.0023x over previous
//
#include <hip/hip_runtime.h>
#include <hip/hip_fp16.h>

// AdaptiveHighPassFilter: conv3x3(64->9, zero-pad) -> softmax(taps) -> hamming
// renorm -> CARAFE(3x3, reflect) -> 2x - lowpass.
//
// R14 = consolidation on the best-measured base (R9, 97.69us):
//   128-thr blocks, 2 waves, __launch_bounds__(128,2), prep kernel, fp16
//   + the two individually-sound ILP changes that were never tested on
//   this base in isolation:
//  (a) 4-deep row ring buffer (from R10): static indices, no destructive
//      rotate (48 v_mov/row killed), prefetch next dy-row right after MFMA
//      so ds_read latency overlaps softmax. Prefetch row <= 9 < TPY=10.
//  (b) dual MFMA accumulator chains (even/odd half): halves the 18-deep
//      dependent-MFMA latency chain.
// Evidence: R12 (256-thr occupancy 2x) +1.0us vs R9; R13 (prep merged
// in-kernel) +0.2us vs R12 with 1.72M new LDS bank conflicts from the
// W-scatter. Both structural theories nulled -> revert to R9 shape.
// Kernel ~10us vs 7.8us BW floor (49.4MB @ 6.3TB/s); fills ~86us fixed.
//
// R9: fp16 pipeline (pk_fma carafe via op_sel, pk epilogue, 16x16x32_f16).
// R7: cvt_pk staging pack. R5-R6: carafe from conv's own B-fragments, mask
// broadcast via 5 shuffles, one barrier, 16x8 tiles, XCD swizzle.

typedef __attribute__((ext_vector_type(8))) short short8;
typedef __attribute__((ext_vector_type(4))) float floatx4;
typedef __attribute__((ext_vector_type(4))) unsigned uint4v;

#define IH 128
#define IW 128
#define CCH 64
#define TSX 16
#define TSY 8
#define TPX 18
#define TPY 10
#define CSH 72   // shorts per position: 144B row, 16B-aligned, bank stride 4

// 1-instruction pack of two f32 -> packed f16x2 (lo = a, hi = b), RTZ
__device__ __forceinline__ unsigned cvtpkh(float a, float b) {
    unsigned r;
    asm("v_cvt_pkrtz_f16_f32 %0, %1, %2" : "=v"(r) : "v"(a), "v"(b));
    return r;
}
// l_pair += x_pair * m.lo   (f16 packed, mask lo-half broadcast via op_sel)
__device__ __forceinline__ unsigned pkfma_lo(unsigned x2, unsigned m2, unsigned acc) {
    unsigned d;
    asm("v_pk_fma_f16 %0, %1, %2, %3 op_sel:[0,0,0] op_sel_hi:[1,0,1]"
        : "=v"(d) : "v"(x2), "v"(m2), "v"(acc));
    return d;
}
// l_pair += x_pair * m.hi
__device__ __forceinline__ unsigned pkfma_hi(unsigned x2, unsigned m2, unsigned acc) {
    unsigned d;
    asm("v_pk_fma_f16 %0, %1, %2, %3 op_sel:[0,1,0] op_sel_hi:[1,1,1]"
        : "=v"(d) : "v"(x2), "v"(m2), "v"(acc));
    return d;
}
// o_pair = c_pair * 2.0 - l_pair   (f16 packed)
__device__ __forceinline__ unsigned pk2xml(unsigned c2, unsigned two2, unsigned l2) {
    unsigned d;
    asm("v_pk_fma_f16 %0, %1, %2, %3 neg_lo:[0,0,1] neg_hi:[0,0,1]"
        : "=v"(d) : "v"(c2), "v"(two2), "v"(l2));
    return d;
}
__device__ __forceinline__ float h2f_lo(unsigned u) {
    return __half2float(__ushort_as_half((unsigned short)(u & 0xFFFFu)));
}
__device__ __forceinline__ float h2f_hi(unsigned u) {
    return __half2float(__ushort_as_half((unsigned short)(u >> 16)));
}
__device__ __forceinline__ unsigned short f2h(float f) {
    return __half_as_ushort(__float2half(f));   // RNE
}

// ---- prep: W[9][64][3][3] f32 -> fp16 A-fragments ws[s][lane][8shorts]
__global__ void ahpf_prep(const float* __restrict__ Wg,
                          unsigned short* __restrict__ wsp)
{
    const int i = blockIdx.x * 256 + threadIdx.x;   // 0..1151
    if (i >= 18 * 64) return;
    const int s = i >> 6, l = i & 63;
    const int fm = l & 15, fq = l >> 4;
    const int tap = s >> 1, cb = (s & 1) * 32 + fq * 8;
    short8 v = (short8)0;
    if (fm < 9) {
#pragma unroll
        for (int jj = 0; jj < 8; ++jj)
            v[jj] = (short)f2h(Wg[fm * 576 + (cb + jj) * 9 + tap]);
    }
    ((short8*)wsp)[i] = v;
}

template <bool USE_WS>
__global__ __launch_bounds__(128, 2) void ahpf_kernel(
    const float* __restrict__ x, const float* __restrict__ Wg,
    const float* __restrict__ bias, float* __restrict__ out,
    const unsigned short* __restrict__ wsp)
{
    __shared__ __align__(16) unsigned short sx[TPY * TPX * CSH];  // 25,920 B

    const int tid  = threadIdx.x;
    const int lane = tid & 63;
    const int wv   = tid >> 6;          // 0..1

    // XCD swizzle: XCD k gets the 128 tiles of image k
    const unsigned flat = blockIdx.x + 8u * (blockIdx.y + 16u * blockIdx.z);
    const unsigned nid  = (flat & 7u) * 128u + (flat >> 3);
    const int bx = nid & 7, by = (nid >> 3) & 15, bz = nid >> 7;

    const int ty0 = by * TSY;
    const int tx0 = bx * TSX;
    const size_t hw = (size_t)IH * IW;
    const float* xb = x + (size_t)bz * CCH * hw;

    const int fm = lane & 15;   // conv: pixel col n / A row m
    const int fq = lane >> 4;

    // ---- A-fragments: 18 coalesced b128 loads from prep ws (or gather fallback)
    short8 afr[18];
    if (USE_WS) {
        const short8* wf = (const short8*)wsp;
#pragma unroll
        for (int s = 0; s < 18; ++s) afr[s] = wf[s * 64 + lane];
    } else {
#pragma unroll
        for (int s = 0; s < 18; ++s) {
            short8 a = (short8)0;
            if (fm < 9) {
                const int tap = s >> 1, cb = (s & 1) * 32 + fq * 8;
                const float* wp = Wg + fm * 576 + tap;
#pragma unroll
                for (int jj = 0; jj < 8; ++jj)
                    a[jj] = (short)f2h(wp[(cb + jj) * 9]);
            }
            afr[s] = a;
        }
    }
    float bq[4];
#pragma unroll
    for (int r = 0; r < 4; ++r) {
        const int t = fq * 4 + r;
        bq[r] = (t < 9) ? bias[t] : 0.0f;
    }

    // ---- stage reflect-padded tile fp16 [pos][c]; slots = 8ch x 4pos
    {
        int gx0 = tx0 - 4;
        if (gx0 < 0) gx0 = 0;
        if (gx0 > IW - 24) gx0 = IW - 24;
        const bool xlo = (bx == 0), xhi = (bx == 7);
        const int cg8 = tid & 7;                 // fixed per thread
#pragma unroll
        for (int it = 0; it < 4; ++it) {
            const int s = it * 128 + tid;        // 480 slots total
            if (s >= 480) break;
            const int u = s >> 3;                // 0..59
            const int y = u / 6, xg = u - 6 * y;
            int gy = ty0 + y - 1;
            gy = gy < 0 ? -gy : (gy >= IH ? 2 * IH - 2 - gy : gy);
            const float* src = xb + (size_t)(cg8 * 8) * hw
                             + (size_t)gy * IW + gx0 + 4 * xg;
            float4 v[8];
#pragma unroll
            for (int jj = 0; jj < 8; ++jj)
                v[jj] = *(const float4*)(src + (size_t)jj * hw);
            const int xbase = gx0 + 4 * xg - tx0 + 1;
#pragma unroll
            for (int e = 0; e < 4; ++e) {
                const float fe[8] = {
                    ((const float*)&v[0])[e], ((const float*)&v[1])[e],
                    ((const float*)&v[2])[e], ((const float*)&v[3])[e],
                    ((const float*)&v[4])[e], ((const float*)&v[5])[e],
                    ((const float*)&v[6])[e], ((const float*)&v[7])[e]};
                uint4v pk;
                pk.x = cvtpkh(fe[0], fe[1]); pk.y = cvtpkh(fe[2], fe[3]);
                pk.z = cvtpkh(fe[4], fe[5]); pk.w = cvtpkh(fe[6], fe[7]);
                const int gxe = gx0 + 4 * xg + e;
                const int xx = xbase + e;
                if (xx >= 0 && xx < TPX)
                    *(uint4v*)&sx[(y * TPX + xx) * CSH + cg8 * 8] = pk;
                if (xlo && gxe == 1)
                    *(uint4v*)&sx[(y * TPX + 0) * CSH + cg8 * 8] = pk;
                if (xhi && gxe == 126)
                    *(uint4v*)&sx[(y * TPX + 17) * CSH + cg8 * 8] = pk;
            }
        }
    }
    __syncthreads();

    const bool border = (bx == 0) | (bx == 7) | (by == 0) | (by == 15);
    const int n = fm;

    // 4-deep dy-row ring buffer; all indices compile-time after unroll.
    // buffer b holds one dy-row: 3 dx positions x 2 ch-halves = 6 frags.
    short8 rbuf[24];
#define FR(dy1, dx1, half) rbuf[(((rr + (dy1)) & 3) * 6) + (dx1) * 2 + (half)]
#define LDSRD(row, dx1, half) \
    (*(const short8*)&sx[((row) * TPX + (n + (dx1))) * CSH + (half) * 32 + fq * 8])

    // carafe: one tap, 16 channels = 8 pk_fma (mask half broadcast by op_sel)
#define CARAFE_TAP(dy1, dx1, qq, HALF)                                       \
    {                                                                        \
        const uint4v A  = *(const uint4v*)&FR(dy1, dx1, 0);                  \
        const uint4v Bv = *(const uint4v*)&FR(dy1, dx1, 1);                  \
        _Pragma("unroll")                                                    \
        for (int u = 0; u < 4; ++u) {                                        \
            l[u]     = pkfma_##HALF(A[u],  qq, l[u]);                        \
            l[4 + u] = pkfma_##HALF(Bv[u], qq, l[4 + u]);                    \
        }                                                                    \
    }

    // ---- per row (4 rows/wave): conv MFMA (dual chains) -> softmax ->
    //      broadcast -> carafe
#pragma unroll
    for (int rr = 0; rr < 4; ++rr) {
        const int R = wv * 4 + rr;
        const int h = ty0 + R, w = tx0 + n;

        if (rr == 0) {
            // fill bufs 0,1,2 with dy-rows R+0,R+1,R+2 (LDS rows)
#pragma unroll
            for (int dy1 = 0; dy1 < 3; ++dy1)
#pragma unroll
                for (int dx1 = 0; dx1 < 3; ++dx1) {
                    FR(dy1, dx1, 0) = LDSRD(R + dy1, dx1, 0);
                    FR(dy1, dx1, 1) = LDSRD(R + dy1, dx1, 1);
                }
        }

        floatx4 ac0 = {0.f, 0.f, 0.f, 0.f};
        floatx4 ac1 = {0.f, 0.f, 0.f, 0.f};
        if (border) {
#pragma unroll
            for (int dy1 = 0; dy1 < 3; ++dy1)
#pragma unroll
                for (int dx1 = 0; dx1 < 3; ++dx1) {
                    const int hy = h + dy1 - 1, wx = w + dx1 - 1;
                    const bool oob = (hy < 0) | (hy >= IH) | (wx < 0) | (wx >= IW);
                    short8 b0 = FR(dy1, dx1, 0);
                    short8 b1 = FR(dy1, dx1, 1);
                    if (oob) { b0 = (short8)0; b1 = (short8)0; }
                    const int s2 = 2 * (3 * dy1 + dx1);
                    ac0 = __builtin_amdgcn_mfma_f32_16x16x32_f16(afr[s2],     b0, ac0, 0, 0, 0);
                    ac1 = __builtin_amdgcn_mfma_f32_16x16x32_f16(afr[s2 + 1], b1, ac1, 0, 0, 0);
                }
        } else {
#pragma unroll
            for (int dy1 = 0; dy1 < 3; ++dy1)
#pragma unroll
                for (int dx1 = 0; dx1 < 3; ++dx1) {
                    const int s2 = 2 * (3 * dy1 + dx1);
                    ac0 = __builtin_amdgcn_mfma_f32_16x16x32_f16(afr[s2],     FR(dy1, dx1, 0), ac0, 0, 0, 0);
                    ac1 = __builtin_amdgcn_mfma_f32_16x16x32_f16(afr[s2 + 1], FR(dy1, dx1, 1), ac1, 0, 0, 0);
                }
        }
        const floatx4 acc = ac0 + ac1;

        // prefetch next row's dy=+1 into the (dead) 4th buffer; max LDS row
        // = wv*4+2+3 = 9 < TPY. lgkm latency overlaps softmax + broadcast.
        if (rr < 3) {
#pragma unroll
            for (int dx1 = 0; dx1 < 3; ++dx1) {
                rbuf[(((rr + 3) & 3) * 6) + dx1 * 2 + 0] = LDSRD(R + 3, dx1, 0);
                rbuf[(((rr + 3) & 3) * 6) + dx1 * 2 + 1] = LDSRD(R + 3, dx1, 1);
            }
        }

        // softmax*hamming, denom-cancelled; lane holds taps fq*4+r of pixel n
        auto hamt = [](int t) {
            const float a = (t / 3 == 1) ? 1.f : 0.08f;
            const float b = (t % 3 == 1) ? 1.f : 0.08f;
            return a * b;
        };
        const int nval = (fq < 2) ? 4 : (fq == 2 ? 1 : 0);
        float e0 = 0, e1 = 0, e2 = 0, e3 = 0, ssum = 0;
        if (nval >= 1) { e0 = __expf(acc[0] + bq[0]) * hamt(fq * 4 + 0); ssum += e0; }
        if (nval >= 4) { e1 = __expf(acc[1] + bq[1]) * hamt(fq * 4 + 1); ssum += e1;
                         e2 = __expf(acc[2] + bq[2]) * hamt(fq * 4 + 2); ssum += e2;
                         e3 = __expf(acc[3] + bq[3]) * hamt(fq * 4 + 3); ssum += e3; }
        ssum += __shfl_xor(ssum, 16);
        ssum += __shfl_xor(ssum, 32);
        const float inv = 1.0f / ssum;

        // broadcast 9 taps to every lane of pixel n as f16 TAP-PAIRS:
        // q0=(m0,m1) q1=(m2,m3) q2=(m4,m5) q3=(m6,m7) q4=(m8,0)
        const unsigned p01 = cvtpkh(e0 * inv, e1 * inv);
        const unsigned p23 = cvtpkh(e2 * inv, e3 * inv);
        const unsigned q0 = (unsigned)__shfl((int)p01, n);
        const unsigned q1 = (unsigned)__shfl((int)p23, n);
        const unsigned q2 = (unsigned)__shfl((int)p01, 16 + n);
        const unsigned q3 = (unsigned)__shfl((int)p23, 16 + n);
        const unsigned q4 = (unsigned)__shfl((int)p01, 32 + n);

        // carafe from registers via packed f16 fma: ch {8fq..}+{32+8fq..}
        unsigned l[8];
#pragma unroll
        for (int i = 0; i < 8; ++i) l[i] = 0u;
        CARAFE_TAP(0, 0, q0, lo);   // tap 0
        CARAFE_TAP(0, 1, q0, hi);   // tap 1
        CARAFE_TAP(0, 2, q1, lo);   // tap 2
        CARAFE_TAP(1, 0, q1, hi);   // tap 3
        CARAFE_TAP(1, 1, q2, lo);   // tap 4
        CARAFE_TAP(1, 2, q2, hi);   // tap 5
        CARAFE_TAP(2, 0, q3, lo);   // tap 6
        CARAFE_TAP(2, 1, q3, hi);   // tap 7
        CARAFE_TAP(2, 2, q4, lo);   // tap 8 (hi mask = 0)

        const uint4v c0 = *(const uint4v*)&FR(1, 1, 0);   // center tap (t=4)
        const uint4v c1 = *(const uint4v*)&FR(1, 1, 1);
        const unsigned TWO2 = 0x40004000u;                // (2.0h, 2.0h)
        float* ob = out + (size_t)bz * CCH * hw + (size_t)h * IW + w
                  + (size_t)(8 * fq) * hw;
#pragma unroll
        for (int q = 0; q < 4; ++q) {
            const unsigned oe = pk2xml(c0[q], TWO2, l[q]);
            const unsigned oo = pk2xml(c1[q], TWO2, l[4 + q]);
            ob[(size_t)(2 * q) * hw]          = h2f_lo(oe);
            ob[(size_t)(2 * q + 1) * hw]      = h2f_hi(oe);
            ob[(size_t)(32 + 2 * q) * hw]     = h2f_lo(oo);
            ob[(size_t)(32 + 2 * q + 1) * hw] = h2f_hi(oo);
        }
    }
#undef CARAFE_TAP
#undef LDSRD
#undef FR
}

extern "C" void kernel_launch(void* const* d_in, const int* in_sizes, int n_in,
                              void* d_out, int out_size, void* d_ws, size_t ws_size,
                              hipStream_t stream) {
    const float* x    = (const float*)d_in[0];
    const float* Wg   = (const float*)d_in[1];
    const float* bias = (const float*)d_in[2];
    float* out        = (float*)d_out;
    const int B = in_sizes[0] / (CCH * IH * IW);
    dim3 grid(8, 16, B);

    if (ws_size >= 18 * 64 * 16) {
        unsigned short* wsp = (unsigned short*)d_ws;
        ahpf_prep<<<5, 256, 0, stream>>>(Wg, wsp);
        ahpf_kernel<true><<<grid, dim3(128, 1, 1), 0, stream>>>(x, Wg, bias, out, wsp);
    } else {
        ahpf_kernel<false><<<grid, dim3(128, 1, 1), 0, stream>>>(x, Wg, bias, out, nullptr);
    }
}